// Round 13
// baseline (737.244 us; speedup 1.0000x reference)
//
#include <hip/hip_runtime.h>
#include <hip/hip_fp16.h>

// B=2048 rows, T=2048 steps, H=32. Wave = ONE batch row; lane = (k, gp).
// gp0 owns gates {i,f}, gp1 owns {g,o}. R13 = R10 + R12 combined:
//  - h broadcast 100% VALU (cvt -> permlane16_swap -> pack -> 15x
//    v_mov_dpp row_ror, depth-1 fan-out, ~20cyc chain) -- ZERO LDS in the
//    step loop (R10-verified correct, was issue-bound on remat tax).
//  - weights pre-packed into d_ws in exact consumption order by a one-wave
//    prep kernel that runs the SAME DPP probe (lane-ids through the gather
//    pipeline) -> fwd kernel does 8 coalesced dwordx4 loads + launder, no
//    per-step rebuild (R12-verified resident: VGPR 88, no spill traffic).

#define Bsz 2048
#define Tsz 2048
#define Hsz 32

typedef _Float16 v2h __attribute__((ext_vector_type(2)));

__device__ __forceinline__ float fast_rcp(float x) { return __builtin_amdgcn_rcpf(x); }
__device__ __forceinline__ float fast_exp2(float x) { return __builtin_amdgcn_exp2f(x); }

__device__ __forceinline__ float fdot2(unsigned a, unsigned b, float c) {
#if __has_builtin(__builtin_amdgcn_fdot2)
    return __builtin_amdgcn_fdot2(__builtin_bit_cast(v2h, a),
                                  __builtin_bit_cast(v2h, b), c, false);
#else
    v2h av = __builtin_bit_cast(v2h, a), bv = __builtin_bit_cast(v2h, b);
    return __fmaf_rn((float)av.x, (float)bv.x,
                     __fmaf_rn((float)av.y, (float)bv.y, c));
#endif
}

// xor-32 exchange; r0 = low-half-origin value (all lanes), r1 = high-half.
__device__ __forceinline__ void plswap(float a, float b, float& r0, float& r1) {
#if __has_builtin(__builtin_amdgcn_permlane32_swap)
    auto r = __builtin_amdgcn_permlane32_swap(__float_as_uint(a), __float_as_uint(b),
                                              false, false);
    r0 = __uint_as_float(r[0]);
    r1 = __uint_as_float(r[1]);
#else
    const bool hi = (threadIdx.x & 32) != 0;
    r0 = hi ? __shfl_xor(b, 32) : a;
    r1 = hi ? b : __shfl_xor(a, 32);
#endif
}

// xor-16 exchange on dwords; r0 = bit4==0-origin, r1 = bit4==1-origin.
__device__ __forceinline__ void pl16(unsigned a, unsigned b, unsigned& r0, unsigned& r1) {
#if __has_builtin(__builtin_amdgcn_permlane16_swap)
    auto r = __builtin_amdgcn_permlane16_swap(a, b, false, false);
    r0 = r[0];
    r1 = r[1];
#else
    const bool hi = (threadIdx.x & 16) != 0;
    r0 = hi ? (unsigned)__shfl_xor((int)a, 16) : a;
    r1 = hi ? b : (unsigned)__shfl_xor((int)b, 16);
#endif
}

template <int N>
__device__ __forceinline__ unsigned ror16(unsigned v) {
    if constexpr (N == 0) return v;
    else
        return (unsigned)__builtin_amdgcn_mov_dpp((int)v, 0x120 + N, 0xf, 0xf, false);
}

__device__ __forceinline__ unsigned pkh(float a, float b) {
    unsigned ua = (unsigned)__builtin_bit_cast(unsigned short, (_Float16)a);
    unsigned ub = (unsigned)__builtin_bit_cast(unsigned short, (_Float16)b);
    return ua | (ub << 16);
}

#define BUILD16(ARR, SRC)                                                    \
    ARR[0]  = SRC;            ARR[1]  = ror16<1>(SRC);                       \
    ARR[2]  = ror16<2>(SRC);  ARR[3]  = ror16<3>(SRC);                       \
    ARR[4]  = ror16<4>(SRC);  ARR[5]  = ror16<5>(SRC);                       \
    ARR[6]  = ror16<6>(SRC);  ARR[7]  = ror16<7>(SRC);                       \
    ARR[8]  = ror16<8>(SRC);  ARR[9]  = ror16<9>(SRC);                       \
    ARR[10] = ror16<10>(SRC); ARR[11] = ror16<11>(SRC);                      \
    ARR[12] = ror16<12>(SRC); ARR[13] = ror16<13>(SRC);                      \
    ARR[14] = ror16<14>(SRC); ARR[15] = ror16<15>(SRC);

// ---- prep: ONE wave. Probe the DPP gather pipeline with lane-ids, then
// pack weight pairs to match the runtime h-dword layout. ws layout:
//   u32 ws[q*256 + lane*4 + d], q<4: row jA (pairs pd[4q+d]), q>=4: row jB
//   float4 ws[2048..]: {w_ih[jA], bias[jA], w_ih[jB], bias[jB]} per lane
__global__ void lstm_prep_kernel(const float* __restrict__ w_ih,
                                 const float* __restrict__ w_hh,
                                 const float* __restrict__ b_ih,
                                 const float* __restrict__ b_hh,
                                 unsigned* __restrict__ ws) {
    const int lane = threadIdx.x & 63;
    unsigned pa, pb;
    pl16((unsigned)lane, (unsigned)lane, pa, pb);
    const unsigned probe0 = (pa & 0xffffu) | (pb << 16);
    unsigned pd[16];
    BUILD16(pd, probe0)

    const int k = lane & 31, gp = lane >> 5;
    const int jA = gp * 64 + k, jB = jA + 32;
    const float* rA = w_hh + (size_t)jA * Hsz;
    const float* rB = w_hh + (size_t)jB * Hsz;
#pragma unroll
    for (int d = 0; d < 16; ++d) {
        const int ia = (int)(pd[d] & 31u);
        const int ib = (int)((pd[d] >> 16) & 31u);
        ws[(d >> 2) * 256 + lane * 4 + (d & 3)]       = pkh(rA[ia], rA[ib]);
        ws[((d >> 2) + 4) * 256 + lane * 4 + (d & 3)] = pkh(rB[ia], rB[ib]);
    }
    float4 v;
    v.x = w_ih[jA]; v.y = b_ih[jA] + b_hh[jA];
    v.z = w_ih[jB]; v.w = b_ih[jB] + b_hh[jB];
    reinterpret_cast<float4*>(ws + 2048)[lane] = v;
}

__global__ __launch_bounds__(256, 2) void lstm_fwd_kernel(
    const float* __restrict__ x,        // (B, T)
    const unsigned* __restrict__ ws,    // packed weights + bias
    float* __restrict__ out)            // (B, T*H)
{
    const int lane = threadIdx.x & 63;
    const int k    = lane & 31;
    const int gp   = lane >> 5;         // 0: gates {i,f} ; 1: gates {g,o}
    const int b    = blockIdx.x * 4 + (threadIdx.x >> 6);

    // ---- pre-packed weights: 8 coalesced dwordx4 loads, zero ALU ----
    unsigned WA[16], WB[16];
    {
        const uint4* wq = reinterpret_cast<const uint4*>(ws) + lane;
#pragma unroll
        for (int q = 0; q < 4; ++q) {
            uint4 u = wq[q * 64];
            WA[4 * q] = u.x; WA[4 * q + 1] = u.y; WA[4 * q + 2] = u.z; WA[4 * q + 3] = u.w;
        }
#pragma unroll
        for (int q = 0; q < 4; ++q) {
            uint4 u = wq[(4 + q) * 64];
            WB[4 * q] = u.x; WB[4 * q + 1] = u.y; WB[4 * q + 2] = u.z; WB[4 * q + 3] = u.w;
        }
    }
    asm volatile("" : "+v"(WA[0]), "+v"(WA[1]), "+v"(WA[2]), "+v"(WA[3]),
                      "+v"(WA[4]), "+v"(WA[5]), "+v"(WA[6]), "+v"(WA[7]));
    asm volatile("" : "+v"(WA[8]), "+v"(WA[9]), "+v"(WA[10]), "+v"(WA[11]),
                      "+v"(WA[12]), "+v"(WA[13]), "+v"(WA[14]), "+v"(WA[15]));
    asm volatile("" : "+v"(WB[0]), "+v"(WB[1]), "+v"(WB[2]), "+v"(WB[3]),
                      "+v"(WB[4]), "+v"(WB[5]), "+v"(WB[6]), "+v"(WB[7]));
    asm volatile("" : "+v"(WB[8]), "+v"(WB[9]), "+v"(WB[10]), "+v"(WB[11]),
                      "+v"(WB[12]), "+v"(WB[13]), "+v"(WB[14]), "+v"(WB[15]));

    const float4 wb = reinterpret_cast<const float4*>(ws + 2048)[lane];
    const float wiA = wb.x, bsA = wb.y, wiB = wb.z, bsB = wb.w;

    // unified activation: a1 = A1*rcp(1+exp2(B1*p)) + C1
    // gp0 -> sigmoid(i), gp1 -> tanh(g); second value always sigmoid
    const float B1 = gp ? -2.885390082f : -1.442695041f;
    const float A1 = gp ? 2.0f : 1.0f;
    const float C1 = gp ? -1.0f : 0.0f;

    float c = 0.0f, h = 0.0f, hprev = 0.0f;

    const float* xrow = x + (size_t)b * Tsz;
    float* op = out + (size_t)b * (size_t)(Tsz * Hsz) + gp * 32 + k;

    float xc[8], xn[8];
#pragma unroll
    for (int j = 0; j < 8; ++j) xc[j] = xrow[j];

#pragma unroll 1
    for (int t0 = 0; t0 < Tsz; t0 += 8) {
        const int tn = (t0 + 8 < Tsz) ? (t0 + 8) : t0;  // clamped (dead last)
#pragma unroll
        for (int j = 0; j < 8; ++j) xn[j] = xrow[tn + j];

#pragma unroll
        for (int u = 0; u < 8; ++u) {
            // ---- all-VALU h gather: cvt + pl16 + pack + 15 dpp rors ----
            const unsigned hbits =
                (unsigned)__builtin_bit_cast(unsigned short, (_Float16)h);
            unsigned ra, rb;
            pl16(hbits, hbits, ra, rb);
            const unsigned D0 = (ra & 0xffffu) | (rb << 16);
            unsigned D[16];
            BUILD16(D, D0)

            // ---- 4 independent 8-deep fdot2 chains (2 per owned gate) ----
            float sA0 = 0.f, sA1 = 0.f, sB0 = 0.f, sB1 = 0.f;
#pragma unroll
            for (int m = 0; m < 8; ++m) {
                sA0 = fdot2(D[m], WA[m], sA0);
                sB0 = fdot2(D[m], WB[m], sB0);
            }
#pragma unroll
            for (int m = 8; m < 16; ++m) {
                sA1 = fdot2(D[m], WA[m], sA1);
                sB1 = fdot2(D[m], WB[m], sB1);
            }
            const float xt = xc[u];
            const float pA = (sA0 + sA1) + __fmaf_rn(wiA, xt, bsA);
            const float pB = (sB0 + sB1) + __fmaf_rn(wiB, xt, bsB);

            // own-pair activations
            const float a1 = __fmaf_rn(A1, fast_rcp(1.0f + fast_exp2(B1 * pA)), C1);
            const float a2 = fast_rcp(1.0f + fast_exp2(-1.442695041f * pB));

            float i_, g_, f_, o_;
            plswap(a1, a1, i_, g_);     // i_ = sig(i), g_ = tanh(g), all lanes
            plswap(a2, a2, f_, o_);     // f_ = sig(f), o_ = sig(o), all lanes

            c = __fmaf_rn(f_, c, i_ * g_);
            const float th =
                __fmaf_rn(2.0f, fast_rcp(1.0f + fast_exp2(-2.885390082f * c)), -1.0f);
            h = o_ * th;

            if (u & 1) {                // paired store: rows t-1 (gp0), t (gp1)
                *op = gp ? h : hprev;
                op += 64;
            } else {
                hprev = h;
            }
        }
#pragma unroll
        for (int j = 0; j < 8; ++j) xc[j] = xn[j];
    }
}

extern "C" void kernel_launch(void* const* d_in, const int* in_sizes, int n_in,
                              void* d_out, int out_size, void* d_ws, size_t ws_size,
                              hipStream_t stream) {
    const float* x    = (const float*)d_in[0];
    const float* w_ih = (const float*)d_in[1];
    const float* w_hh = (const float*)d_in[2];
    const float* b_ih = (const float*)d_in[3];
    const float* b_hh = (const float*)d_in[4];
    float* out   = (float*)d_out;
    unsigned* ws = (unsigned*)d_ws;     // needs 9216 B

    lstm_prep_kernel<<<1, 64, 0, stream>>>(w_ih, w_hh, b_ih, b_hh, ws);

    dim3 grid(Bsz / 4);   // 512 blocks = 2 per CU -> 2 waves/SIMD
    dim3 block(256);      // 4 waves, each = one batch row (32 k x 2 gate-pairs)
    lstm_fwd_kernel<<<grid, block, 0, stream>>>(x, ws, out);
}